// Round 1
// baseline (1696.801 us; speedup 1.0000x reference)
//
#include <hip/hip_runtime.h>

#define TT 512
#define BB 256
#define CC 65
#define HALFC 32
#define HID 128
#define ODIM 10

__device__ __forceinline__ float ftanh(float x) {
  float e = __expf(-2.f * fabsf(x));
  float r = (1.f - e) / (1.f + e);
  return copysignf(r, x);
}
__device__ __forceinline__ float fsig(float x) {
  float e = __expf(-fabsf(x));
  float p = 1.f / (1.f + e);
  return (x >= 0.f) ? p : (1.f - p);
}

// Per-t scalars: idx (int bits), fr, td, tsub
__global__ void prep0(const float* __restrict__ times, float4* __restrict__ si,
                      int* __restrict__ anyobs) {
  __shared__ float ts[TT];
  int t = threadIdx.x;
  ts[t] = times[t];
  __syncthreads();
  float tv = ts[t];
  int cnt = 0;
  for (int jj = 0; jj < TT; ++jj) cnt += (tv > ts[jj]) ? 1 : 0;
  int idx = cnt - 1;
  idx = min(max(idx, 0), TT - 2);
  float4 o;
  o.x = __int_as_float(idx);
  o.y = tv - ts[idx];
  o.z = (t == 0) ? 0.f : (tv - ts[t - 1]);
  o.w = (t == 0) ? ts[0] : ts[t - 1];
  si[t] = o;
  anyobs[t] = 0;
}

// obs[b,t] = max over diffed channels 1..32 > 0.5 ; anyobs[t] = OR over b
__global__ void prep_obs(const float* __restrict__ ca, const float* __restrict__ cb,
                         const float* __restrict__ cc2, const float* __restrict__ cd,
                         const float4* __restrict__ si, int* __restrict__ anyobs,
                         unsigned char* __restrict__ obs) {
  int grp = blockIdx.x * (blockDim.x >> 5) + (threadIdx.x >> 5);
  int lane = threadIdx.x & 31;
  int t = grp & (TT - 1);
  int b = grp / TT;
  int ch = 1 + lane;
  float4 s = si[t];
  int idx = __float_as_int(s.x);
  float fr = s.y;
  size_t base = ((size_t)b * (TT - 1) + idx) * CC + ch;
  float f3 = fr / 3.f;
  float v = ca[base] + (cb[base] + (0.5f * cc2[base] + cd[base] * f3) * fr) * fr;
  float D = v;
  if (t >= 1) {
    float4 sp = si[t - 1];
    int idxp = __float_as_int(sp.x);
    float frp = sp.y;
    size_t basep = ((size_t)b * (TT - 1) + idxp) * CC + ch;
    float f3p = frp / 3.f;
    float vp = ca[basep] + (cb[basep] + (0.5f * cc2[basep] + cd[basep] * f3p) * frp) * frp;
    D = v - vp;
  }
  float m = D;
  #pragma unroll
  for (int off = 16; off >= 1; off >>= 1) m = fmaxf(m, __shfl_xor(m, off));
  if (lane == 0) {
    unsigned char o = (m > 0.5f) ? (unsigned char)1 : (unsigned char)0;
    obs[(size_t)b * TT + t] = o;
    if (o) atomicOr(&anyobs[t], 1);
  }
}

// One block per batch element. 512 threads: wave w owns outputs w*16..w*16+15,
// lane kk = lane>>4 covers k-slice kk*32..kk*32+31. Weights in registers.
__launch_bounds__(512, 2)
__global__ void ode_main(
    const float* __restrict__ ca, const float* __restrict__ cb,
    const float* __restrict__ cc2, const float* __restrict__ cd,
    const int* __restrict__ final_index,
    const float* __restrict__ Wr, const float* __restrict__ br,
    const float* __restrict__ Wz, const float* __restrict__ bz,
    const float* __restrict__ Wxn, const float* __restrict__ bxn,
    const float* __restrict__ Whn, const float* __restrict__ bhn,
    const float* __restrict__ Wode, const float* __restrict__ bode,
    const float* __restrict__ Wlin, const float* __restrict__ blin,
    const float4* __restrict__ si, const int* __restrict__ anyobs,
    const unsigned char* __restrict__ obsArr,
    float* __restrict__ out)
{
  __shared__ alignas(16) float hA[HID];
  __shared__ alignas(16) float hB[HID];
  __shared__ alignas(16) float vA[HID];
  __shared__ alignas(16) float vB[HID];
  __shared__ alignas(16) float xs[HALFC];

  const int tid = threadIdx.x;
  const int b = blockIdx.x;
  const int lane = tid & 63;
  const int wv = tid >> 6;
  const int oo = lane & 15;
  const int kk = lane >> 4;
  const int j = wv * 16 + oo;
  const int kbase = kk * 32;
  const int kx = kk * 8;

  // Register-resident weight columns (chunk-rotated by kk*2 for LDS bank spread)
  float wode[32], whn[32], wrh[32], wzh[32];
  float wrx[8], wzx[8], wxn[8];
  #pragma unroll
  for (int q = 0; q < 8; ++q) {
    const int c = ((kk * 2 + q) & 7) * 4;
    #pragma unroll
    for (int e = 0; e < 4; ++e) {
      const int row = kbase + c + e;
      wode[q * 4 + e] = Wode[row * HID + j];
      whn [q * 4 + e] = Whn [row * HID + j];
      wrh [q * 4 + e] = Wr[(HALFC + row) * HID + j];
      wzh [q * 4 + e] = Wz[(HALFC + row) * HID + j];
    }
  }
  #pragma unroll
  for (int i = 0; i < 8; ++i) {
    wrx[i] = Wr [(kx + i) * HID + j];
    wzx[i] = Wz [(kx + i) * HID + j];
    wxn[i] = Wxn[(kx + i) * HID + j];
  }
  const float bo = bode[j], bh = bhn[j], brj = br[j], bzj = bz[j], bxj = bxn[j];
  const int fidx = final_index[b];

  if (tid < HID) { hA[tid] = 0.f; hB[tid] = 0.f; vA[tid] = 0.f; vB[tid] = 0.f; }
  if (tid < HALFC) xs[tid] = 0.f;
  float hj = 0.f;   // this thread's h[j] (replicated across the 4 kk lanes)
  float dt = 0.f;   // meaningful on thread 0 only
  __syncthreads();

  auto part128 = [&](const float* vsrc, const float (&wcol)[32]) -> float {
    const float4* v4 = (const float4*)vsrc;
    float p0 = 0.f, p1 = 0.f, p2 = 0.f, p3 = 0.f;
    #pragma unroll
    for (int q = 0; q < 8; ++q) {
      float4 vv = v4[kk * 8 + ((kk * 2 + q) & 7)];
      p0 = fmaf(vv.x, wcol[q * 4 + 0], p0);
      p1 = fmaf(vv.y, wcol[q * 4 + 1], p1);
      p2 = fmaf(vv.z, wcol[q * 4 + 2], p2);
      p3 = fmaf(vv.w, wcol[q * 4 + 3], p3);
    }
    return (p0 + p1) + (p2 + p3);
  };
  auto red4 = [&](float p) -> float {
    p += __shfl_xor(p, 16);
    p += __shfl_xor(p, 32);
    return p;
  };

  for (int t = 0; ; ++t) {
    const float4 s = si[t];
    const int sidx = __float_as_int(s.x);
    const float fr = s.y, td = s.z, tsub = s.w;
    const int aob = anyobs[t];
    const int ob = (int)obsArr[(size_t)b * TT + t];
    const bool apply = (aob != 0) && (ob != 0);

    // Issue x-coeff loads early (wave 0, lanes 0..31); consumed after RK4.
    float xa = 0.f, xb = 0.f, xc = 0.f, xd = 0.f;
    float ya = 0.f, yb = 0.f, yc = 0.f, yd = 0.f;
    const bool xlane = (wv == 0) && (lane < 32);
    if (xlane) {
      const size_t base = ((size_t)b * (TT - 1) + sidx) * CC;
      const int ch = 33 + lane;
      xa = ca[base + ch]; xb = cb[base + ch]; xc = cc2[base + ch]; xd = cd[base + ch];
      if (lane == 0) { ya = ca[base]; yb = cb[base]; yc = cc2[base]; yd = cd[base]; }
    }

    if (t > 0) {
      // RK4 evolve: h -> vB (h_evolved)
      const float* hcur = (t & 1) ? hB : hA;
      float k1 = ftanh(red4(part128(hcur, wode)) + bo);
      float ks = k1;
      if (kk == 0) vA[j] = fmaf(0.5f * td, k1, hj);
      __syncthreads();
      float k2 = ftanh(red4(part128(vA, wode)) + bo);
      ks = fmaf(2.f, k2, ks);
      if (kk == 0) vB[j] = fmaf(0.5f * td, k2, hj);
      __syncthreads();
      float k3 = ftanh(red4(part128(vB, wode)) + bo);
      ks = fmaf(2.f, k3, ks);
      if (kk == 0) vA[j] = fmaf(td, k3, hj);
      __syncthreads();
      float k4 = ftanh(red4(part128(vA, wode)) + bo);
      ks += k4;
      hj = fmaf(td * (1.f / 6.f), ks, hj);
      if (kk == 0) vB[j] = hj;
    }

    // Spline -> x (wave 0). vB now holds h_evolved (zeros at t=0).
    float xdelta = 0.f;
    if (xlane) {
      const float f3 = fr / 3.f;
      float sv = xa + (xb + (0.5f * xc + xd * f3) * fr) * fr;
      if (lane == 0) {
        float s0 = ya + (yb + (0.5f * yc + yd * f3) * fr) * fr;
        xdelta = s0 - tsub;
        sv += dt;   // Xp[:,0] += dt
      }
      xs[lane] = sv;
    }
    __syncthreads();

    // GRU stage: r, z, n in one pass
    float rp = part128(vB, wrh);
    float zp = part128(vB, wzh);
    float hp = part128(vB, whn);
    float xp = 0.f;
    {
      const float4* x4 = (const float4*)xs;
      float4 u0 = x4[kk * 2], u1 = x4[kk * 2 + 1];
      float ux[8] = {u0.x, u0.y, u0.z, u0.w, u1.x, u1.y, u1.z, u1.w};
      #pragma unroll
      for (int i2 = 0; i2 < 8; ++i2) {
        rp = fmaf(ux[i2], wrx[i2], rp);
        zp = fmaf(ux[i2], wzx[i2], zp);
        xp = fmaf(ux[i2], wxn[i2], xp);
      }
    }
    rp = red4(rp); zp = red4(zp); hp = red4(hp); xp = red4(xp);
    const float r = fsig(rp + brj);
    const float z = fsig(zp + bzj);
    const float n = ftanh(xp + bxj + (hp + bh) * r);
    const float hnew = fmaf(z, hj - n, n);   // (1-z)*n + z*h
    if (apply) hj = hnew;
    float* hnext = (t & 1) ? hA : hB;
    if (kk == 0) hnext[j] = hj;
    if (tid == 0 && aob && !ob) dt += xdelta;
    __syncthreads();
    if (t == fidx) break;
  }

  // final projection: out = h @ W_lin + b_lin
  const float* hf = (fidx & 1) ? hA : hB;
  if (tid < ODIM) {
    float acc = blin[tid];
    #pragma unroll 8
    for (int q = 0; q < HID; ++q) acc = fmaf(hf[q], Wlin[q * ODIM + tid], acc);
    out[b * ODIM + tid] = acc;
  }
}

extern "C" void kernel_launch(void* const* d_in, const int* in_sizes, int n_in,
                              void* d_out, int out_size, void* d_ws, size_t ws_size,
                              hipStream_t stream) {
  const float* times = (const float*)d_in[0];
  const float* ca   = (const float*)d_in[1];
  const float* cb   = (const float*)d_in[2];
  const float* cc2  = (const float*)d_in[3];
  const float* cd   = (const float*)d_in[4];
  const int*   fidx = (const int*)d_in[5];
  const float* Wr   = (const float*)d_in[6];
  const float* br   = (const float*)d_in[7];
  const float* Wz   = (const float*)d_in[8];
  const float* bz   = (const float*)d_in[9];
  const float* Wxn  = (const float*)d_in[10];
  const float* bxn  = (const float*)d_in[11];
  const float* Whn  = (const float*)d_in[12];
  const float* bhn  = (const float*)d_in[13];
  const float* Wode = (const float*)d_in[14];
  const float* bode = (const float*)d_in[15];
  const float* Wlin = (const float*)d_in[16];
  const float* blin = (const float*)d_in[17];
  float* out = (float*)d_out;

  char* ws = (char*)d_ws;
  float4* si = (float4*)ws;                                  // TT*16 B
  int* anyobs = (int*)(ws + TT * 16);                        // TT*4 B
  unsigned char* obs = (unsigned char*)(ws + TT * 16 + TT * 4); // BB*TT B

  prep0<<<1, TT, 0, stream>>>(times, si, anyobs);
  prep_obs<<<(BB * TT) / 8, 256, 0, stream>>>(ca, cb, cc2, cd, si, anyobs, obs);
  ode_main<<<BB, 512, 0, stream>>>(ca, cb, cc2, cd, fidx, Wr, br, Wz, bz,
                                   Wxn, bxn, Whn, bhn, Wode, bode, Wlin, blin,
                                   si, anyobs, obs, out);
}